// Round 1
// baseline (2913.493 us; speedup 1.0000x reference)
//
#include <hip/hip_runtime.h>

#define B_  64
#define S_  128
#define H_  1024
#define V_  32000
#define T_  10

typedef unsigned short ushort_t;
typedef unsigned int uint32;
typedef __attribute__((ext_vector_type(8))) short bf16x8;
typedef __attribute__((ext_vector_type(4))) float f32x4;

__device__ __forceinline__ ushort_t f2bf(float x) {
    uint32 u = __float_as_uint(x);
    u += 0x7fffu + ((u >> 16) & 1u);
    return (ushort_t)(u >> 16);
}
__device__ __forceinline__ float bf2f(ushort_t h) {
    return __uint_as_float(((uint32)h) << 16);
}
__device__ __forceinline__ uint32 pk2(float a, float b) {
    return (uint32)f2bf(a) | ((uint32)f2bf(b) << 16);
}

// ---------------------------------------------------------------------------
// Generic MFMA GEMM:  C[M,N] = A[M,K] @ Bt[N,K]^T + bias[N]
// A is f32 (converted to bf16 hi(+lo) during staging).
// Bt is f32 (split-staged) if !B_BF16, else pre-cast bf16 (copied).
// SPLIT: 3-term bf16x2 product (~fp32 accuracy).
// Optional second operand set used for blocks with n0 >= N1 (fused gi|gh).
// ---------------------------------------------------------------------------
template<int BM, int BN, int WR, int WC, bool SPLIT, bool B_BF16>
__launch_bounds__(256)
__global__ void gemm_bt(const float* __restrict__ A1, const void* __restrict__ B1,
                        const float* __restrict__ bias1, int K1, int N1,
                        const float* __restrict__ A2, const void* __restrict__ B2,
                        const float* __restrict__ bias2, int K2,
                        float* __restrict__ C, int ldc)
{
    constexpr int BK  = 32;
    constexpr int LDK = 40;                       // padded LDS row (bf16 elems), 80B
    constexpr int ASZ = (SPLIT ? 2 : 1) * BM * LDK;
    constexpr int BSZ = (SPLIT ? 2 : 1) * BN * LDK;
    __shared__ ushort_t lds[ASZ + BSZ];
    ushort_t* ldsAh = lds;
    ushort_t* ldsAl = lds + BM * LDK;
    ushort_t* ldsBh = lds + ASZ;
    ushort_t* ldsBl = lds + ASZ + BN * LDK;

    const int tid = threadIdx.x;
    const int m0  = blockIdx.y * BM;
    const int n0  = blockIdx.x * BN;

    const float* A = A1; const void* Bv = B1; const float* bias = bias1;
    int K = K1; int bn0 = n0;
    if (A2 != nullptr && n0 >= N1) { A = A2; Bv = B2; bias = bias2; K = K2; bn0 = n0 - N1; }

    constexpr int MF = BM / WR / 16;
    constexpr int NF = BN / WC / 16;
    const int wid  = tid >> 6;
    const int wrow = wid / WC, wcol = wid % WC;
    const int mW = wrow * (BM / WR);
    const int nW = wcol * (BN / WC);
    const int lane = tid & 63;
    const int lr = lane & 15;     // row within 16 (A) / col (B,C)
    const int lk = lane >> 4;     // k-group of 8

    f32x4 acc[MF][NF];
    #pragma unroll
    for (int i = 0; i < MF; i++)
        #pragma unroll
        for (int j = 0; j < NF; j++)
            acc[i][j] = (f32x4){0.f, 0.f, 0.f, 0.f};

    for (int k0 = 0; k0 < K; k0 += BK) {
        __syncthreads();
        // ---- stage A tile [BM x 32] ----
        for (int c = tid; c < BM * 4; c += 256) {
            int row = c >> 2, slot = c & 3;
            const float* src = A + (size_t)(m0 + row) * K + k0 + slot * 8;
            float4 x0 = *(const float4*)src;
            float4 x1 = *(const float4*)(src + 4);
            uint4 hv;
            hv.x = pk2(x0.x, x0.y); hv.y = pk2(x0.z, x0.w);
            hv.z = pk2(x1.x, x1.y); hv.w = pk2(x1.z, x1.w);
            *(uint4*)&ldsAh[row * LDK + slot * 8] = hv;
            if (SPLIT) {
                uint4 lv;
                lv.x = pk2(x0.x - bf2f((ushort_t)(hv.x & 0xffff)), x0.y - bf2f((ushort_t)(hv.x >> 16)));
                lv.y = pk2(x0.z - bf2f((ushort_t)(hv.y & 0xffff)), x0.w - bf2f((ushort_t)(hv.y >> 16)));
                lv.z = pk2(x1.x - bf2f((ushort_t)(hv.z & 0xffff)), x1.y - bf2f((ushort_t)(hv.z >> 16)));
                lv.w = pk2(x1.z - bf2f((ushort_t)(hv.w & 0xffff)), x1.w - bf2f((ushort_t)(hv.w >> 16)));
                *(uint4*)&ldsAl[row * LDK + slot * 8] = lv;
            }
        }
        // ---- stage B tile [BN x 32] ----
        for (int c = tid; c < BN * 4; c += 256) {
            int row = c >> 2, slot = c & 3;
            if (B_BF16) {
                const ushort_t* src = (const ushort_t*)Bv + (size_t)(bn0 + row) * K + k0 + slot * 8;
                *(uint4*)&ldsBh[row * LDK + slot * 8] = *(const uint4*)src;
            } else {
                const float* src = (const float*)Bv + (size_t)(bn0 + row) * K + k0 + slot * 8;
                float4 x0 = *(const float4*)src;
                float4 x1 = *(const float4*)(src + 4);
                uint4 hv;
                hv.x = pk2(x0.x, x0.y); hv.y = pk2(x0.z, x0.w);
                hv.z = pk2(x1.x, x1.y); hv.w = pk2(x1.z, x1.w);
                *(uint4*)&ldsBh[row * LDK + slot * 8] = hv;
                if (SPLIT) {
                    uint4 lv;
                    lv.x = pk2(x0.x - bf2f((ushort_t)(hv.x & 0xffff)), x0.y - bf2f((ushort_t)(hv.x >> 16)));
                    lv.y = pk2(x0.z - bf2f((ushort_t)(hv.y & 0xffff)), x0.w - bf2f((ushort_t)(hv.y >> 16)));
                    lv.z = pk2(x1.x - bf2f((ushort_t)(hv.z & 0xffff)), x1.y - bf2f((ushort_t)(hv.z >> 16)));
                    lv.w = pk2(x1.z - bf2f((ushort_t)(hv.w & 0xffff)), x1.w - bf2f((ushort_t)(hv.w >> 16)));
                    *(uint4*)&ldsBl[row * LDK + slot * 8] = lv;
                }
            }
        }
        __syncthreads();
        // ---- fragments + MFMA ----
        bf16x8 aH[MF], bH[NF], aL[MF], bL[NF];
        #pragma unroll
        for (int i = 0; i < MF; i++) {
            aH[i] = *(const bf16x8*)&ldsAh[(mW + i * 16 + lr) * LDK + lk * 8];
            if (SPLIT) aL[i] = *(const bf16x8*)&ldsAl[(mW + i * 16 + lr) * LDK + lk * 8];
        }
        #pragma unroll
        for (int j = 0; j < NF; j++) {
            bH[j] = *(const bf16x8*)&ldsBh[(nW + j * 16 + lr) * LDK + lk * 8];
            if (SPLIT) bL[j] = *(const bf16x8*)&ldsBl[(nW + j * 16 + lr) * LDK + lk * 8];
        }
        #pragma unroll
        for (int i = 0; i < MF; i++)
            #pragma unroll
            for (int j = 0; j < NF; j++) {
                acc[i][j] = __builtin_amdgcn_mfma_f32_16x16x32_bf16(aH[i], bH[j], acc[i][j], 0, 0, 0);
                if (SPLIT) {
                    acc[i][j] = __builtin_amdgcn_mfma_f32_16x16x32_bf16(aH[i], bL[j], acc[i][j], 0, 0, 0);
                    acc[i][j] = __builtin_amdgcn_mfma_f32_16x16x32_bf16(aL[i], bH[j], acc[i][j], 0, 0, 0);
                }
            }
    }
    // ---- epilogue: C/D layout col = lane&15, row = (lane>>4)*4 + reg ----
    #pragma unroll
    for (int i = 0; i < MF; i++)
        #pragma unroll
        for (int j = 0; j < NF; j++)
            #pragma unroll
            for (int r = 0; r < 4; r++) {
                int gr = m0 + mW + i * 16 + lk * 4 + r;
                int lc = nW + j * 16 + lr;          // col within block
                float v = acc[i][j][r] + bias[bn0 + lc];
                C[(size_t)gr * ldc + (n0 + lc)] = v;
            }
}

// ---------------------------------------------------------------------------
__global__ __launch_bounds__(256) void cast_bf16_k(const float* __restrict__ in,
                                                   ushort_t* __restrict__ out, int n8)
{
    int i = blockIdx.x * 256 + threadIdx.x;
    if (i < n8) {
        float4 a = ((const float4*)in)[2 * i];
        float4 b = ((const float4*)in)[2 * i + 1];
        uint4 v;
        v.x = pk2(a.x, a.y); v.y = pk2(a.z, a.w);
        v.z = pk2(b.x, b.y); v.w = pk2(b.z, b.w);
        ((uint4*)out)[i] = v;
    }
}

// score[b,s] = Va . tanh(q[b]+Uk[b,s]) + Va_b
__global__ __launch_bounds__(256) void score_k(const float* __restrict__ Uk,
                                               const float* __restrict__ q,
                                               const float* __restrict__ Va_w,
                                               const float* __restrict__ Va_b,
                                               float* __restrict__ scores)
{
    int s = blockIdx.x, b = blockIdx.y;
    int tid = threadIdx.x;
    float4 u  = ((const float4*)(Uk + ((size_t)b * S_ + s) * H_))[tid];
    float4 qq = ((const float4*)(q + (size_t)b * H_))[tid];
    float4 v  = ((const float4*)Va_w)[tid];
    float acc = v.x * tanhf(u.x + qq.x) + v.y * tanhf(u.y + qq.y)
              + v.z * tanhf(u.z + qq.z) + v.w * tanhf(u.w + qq.w);
    for (int off = 32; off > 0; off >>= 1) acc += __shfl_down(acc, off, 64);
    __shared__ float part[4];
    if ((tid & 63) == 0) part[tid >> 6] = acc;
    __syncthreads();
    if (tid == 0) scores[b * S_ + s] = part[0] + part[1] + part[2] + part[3] + Va_b[0];
}

// softmax over S + ctx = w @ enc + write attn row
__global__ __launch_bounds__(256) void softctx_k(const float* __restrict__ scores,
                                                 const float* __restrict__ enc,
                                                 float* __restrict__ ctx,
                                                 float* __restrict__ attn_out, int t)
{
    int hc = blockIdx.x, b = blockIdx.y;
    int tid = threadIdx.x;
    __shared__ float sc[S_], el[S_];
    if (tid < S_) sc[tid] = scores[b * S_ + tid];
    __syncthreads();
    float mx = -1e30f;
    for (int s = 0; s < S_; s++) mx = fmaxf(mx, sc[s]);
    if (tid < S_) el[tid] = expf(sc[tid] - mx);
    __syncthreads();
    float sum = 0.f;
    for (int s = 0; s < S_; s++) sum += el[s];
    float inv = 1.f / sum;
    int h = hc * 256 + tid;
    const float* ep = enc + (size_t)b * S_ * H_ + h;
    float acc = 0.f;
    for (int s = 0; s < S_; s++) acc += el[s] * ep[(size_t)s * H_];
    ctx[(size_t)b * H_ + h] = acc * inv;
    if (hc == 0 && tid < S_) attn_out[((size_t)b * T_ + t) * S_ + tid] = el[tid] * inv;
}

// x = [emb_W[tok], ctx]
__global__ __launch_bounds__(256) void xprep_k(const int* __restrict__ target,
                                               const float* __restrict__ emb_W,
                                               const float* __restrict__ ctx,
                                               float* __restrict__ x, int t)
{
    int i = blockIdx.x * 256 + threadIdx.x;   // B*2H
    int b = i >> 11, k = i & 2047;
    float v;
    if (k < H_) {
        int tok = (t == 0) ? 0 : target[b * T_ + t - 1];
        v = emb_W[(size_t)tok * H_ + k];
    } else {
        v = ctx[(size_t)b * H_ + (k - H_)];
    }
    x[i] = v;
}

// GRU combine
__global__ __launch_bounds__(256) void combine_k(const float* __restrict__ gates,
                                                 const float* __restrict__ hprev,
                                                 float* __restrict__ hnext,
                                                 float* __restrict__ out_hidden)
{
    int i = blockIdx.x * 256 + threadIdx.x;   // B*H
    int b = i >> 10, g = i & 1023;
    const float* gp = gates + (size_t)b * 6144;
    float ir = gp[g],        iz = gp[g + 1024], in = gp[g + 2048];
    float hr = gp[g + 3072], hz = gp[g + 4096], hn_ = gp[g + 5120];
    float h = hprev[i];
    float r = 1.f / (1.f + expf(-(ir + hr)));
    float z = 1.f / (1.f + expf(-(iz + hz)));
    float n = tanhf(in + r * hn_);
    float hn = (1.f - z) * n + z * h;
    hnext[i] = hn;
    if (out_hidden) out_hidden[i] = hn;
}

// in-place log_softmax over V per row
__global__ __launch_bounds__(256) void lsm_k(float* __restrict__ out)
{
    float* p = out + (size_t)blockIdx.x * V_;
    int tid = threadIdx.x;
    float mx = -1e30f, sm = 0.f;
    for (int v = tid; v < V_; v += 256) {
        float x = p[v];
        float m2 = fmaxf(mx, x);
        sm = sm * expf(mx - m2) + expf(x - m2);
        mx = m2;
    }
    for (int off = 32; off > 0; off >>= 1) {
        float mo = __shfl_down(mx, off, 64);
        float so = __shfl_down(sm, off, 64);
        float m2 = fmaxf(mx, mo);
        sm = sm * expf(mx - m2) + so * expf(mo - m2);
        mx = m2;
    }
    __shared__ float pm[4], ps[4];
    __shared__ float lse_s;
    if ((tid & 63) == 0) { pm[tid >> 6] = mx; ps[tid >> 6] = sm; }
    __syncthreads();
    if (tid == 0) {
        float m = pm[0], s = ps[0];
        for (int i = 1; i < 4; i++) {
            float m2 = fmaxf(m, pm[i]);
            s = s * expf(m - m2) + ps[i] * expf(pm[i] - m2);
            m = m2;
        }
        lse_s = m + logf(s);
    }
    __syncthreads();
    float lse = lse_s;
    for (int v = tid; v < V_; v += 256) p[v] -= lse;
}

// ---------------------------------------------------------------------------
extern "C" void kernel_launch(void* const* d_in, const int* in_sizes, int n_in,
                              void* d_out, int out_size, void* d_ws, size_t ws_size,
                              hipStream_t stream)
{
    (void)in_sizes; (void)n_in; (void)out_size; (void)ws_size;
    const float* enc    = (const float*)d_in[0];
    const float* hidden = (const float*)d_in[1];
    const int*   target = (const int*)d_in[2];
    const float* emb_W  = (const float*)d_in[3];
    const float* Wa_w   = (const float*)d_in[4];
    const float* Wa_b   = (const float*)d_in[5];
    const float* Ua_w   = (const float*)d_in[6];
    const float* Ua_b   = (const float*)d_in[7];
    const float* Va_w   = (const float*)d_in[8];
    const float* Va_b   = (const float*)d_in[9];
    const float* W_ih   = (const float*)d_in[10];
    const float* W_hh   = (const float*)d_in[11];
    const float* b_ih   = (const float*)d_in[12];
    const float* b_hh   = (const float*)d_in[13];
    const float* out_W  = (const float*)d_in[14];
    const float* out_b  = (const float*)d_in[15];

    float* out_logits = (float*)d_out;                       // [B,T,V]
    float* out_hidden = out_logits + (size_t)B_ * T_ * V_;   // [B,H]
    float* out_attn   = out_hidden + (size_t)B_ * H_;        // [B,T,S]

    char* w = (char*)d_ws;
    ushort_t* outW_bf = (ushort_t*)w;  w += (size_t)V_ * H_ * 2;
    float* Uk     = (float*)w;         w += (size_t)B_ * S_ * H_ * 4;
    float* q      = (float*)w;         w += (size_t)B_ * H_ * 4;
    float* scores = (float*)w;         w += (size_t)B_ * S_ * 4;
    float* ctx    = (float*)w;         w += (size_t)B_ * H_ * 4;
    float* x      = (float*)w;         w += (size_t)B_ * 2 * H_ * 4;
    float* gates  = (float*)w;         w += (size_t)B_ * 6 * H_ * 4;
    float* h0     = (float*)w;         w += (size_t)B_ * H_ * 4;
    float* h1     = (float*)w;         w += (size_t)B_ * H_ * 4;

    // pre-pass: cast out_W to bf16; Uk = enc @ Ua^T + Ua_b; h0 = hidden
    cast_bf16_k<<<V_ * H_ / 8 / 256, 256, 0, stream>>>(out_W, outW_bf, V_ * H_ / 8);
    gemm_bt<128, 128, 2, 2, true, false><<<dim3(H_ / 128, B_ * S_ / 128), 256, 0, stream>>>(
        enc, (const void*)Ua_w, Ua_b, H_, 1 << 30,
        nullptr, nullptr, nullptr, 0, Uk, H_);
    hipMemcpyAsync(h0, hidden, (size_t)B_ * H_ * 4, hipMemcpyDeviceToDevice, stream);

    for (int t = 0; t < T_; t++) {
        float* hc = (t & 1) ? h1 : h0;
        float* hx = (t & 1) ? h0 : h1;
        // q = hc @ Wa^T + Wa_b   (split, fp32-accurate)
        gemm_bt<64, 128, 1, 4, true, false><<<dim3(H_ / 128, 1), 256, 0, stream>>>(
            hc, (const void*)Wa_w, Wa_b, H_, 1 << 30,
            nullptr, nullptr, nullptr, 0, q, H_);
        score_k<<<dim3(S_, B_), 256, 0, stream>>>(Uk, q, Va_w, Va_b, scores);
        softctx_k<<<dim3(H_ / 256, B_), 256, 0, stream>>>(scores, enc, ctx, out_attn, t);
        xprep_k<<<B_ * 2 * H_ / 256, 256, 0, stream>>>(target, emb_W, ctx, x, t);
        // gates: cols [0,3072) = x@W_ih^T + b_ih ; cols [3072,6144) = hc@W_hh^T + b_hh
        gemm_bt<64, 128, 1, 4, true, false><<<dim3(6 * H_ / 128, 1), 256, 0, stream>>>(
            x, (const void*)W_ih, b_ih, 2 * H_, 3 * H_,
            hc, (const void*)W_hh, b_hh, H_, gates, 6 * H_);
        combine_k<<<B_ * H_ / 256, 256, 0, stream>>>(gates, hc, hx,
                                                     (t == T_ - 1) ? out_hidden : nullptr);
        // logits -> d_out[:, t, :]  (plain bf16, threshold 0.246 has huge headroom)
        gemm_bt<64, 128, 1, 4, false, true><<<dim3(V_ / 128, 1), 256, 0, stream>>>(
            hx, (const void*)outW_bf, out_b, H_, 1 << 30,
            nullptr, nullptr, nullptr, 0, out_logits + (size_t)t * V_, T_ * V_);
    }
    lsm_k<<<B_ * T_, 256, 0, stream>>>(out_logits);
}

// Round 2
// 1188.484 us; speedup vs baseline: 2.4514x; 2.4514x over previous
//
#include <hip/hip_runtime.h>

#define B_  64
#define S_  128
#define H_  1024
#define V_  32000
#define T_  10

typedef unsigned short ushort_t;
typedef unsigned int uint32;
typedef __attribute__((ext_vector_type(8))) short bf16x8;
typedef __attribute__((ext_vector_type(4))) float f32x4;

__device__ __forceinline__ ushort_t f2bf(float x) {
    uint32 u = __float_as_uint(x);
    u += 0x7fffu + ((u >> 16) & 1u);
    return (ushort_t)(u >> 16);
}
__device__ __forceinline__ float bf2f(ushort_t h) {
    return __uint_as_float(((uint32)h) << 16);
}
__device__ __forceinline__ uint32 pk2(float a, float b) {
    return (uint32)f2bf(a) | ((uint32)f2bf(b) << 16);
}

// ---------------------------------------------------------------------------
// MFMA GEMM:  C[M,N] = A[M,K] @ Bt[N,K]^T (+ bias)
//   A: f32, lda == K. Bt: f32 (split-staged) or bf16, row stride ldb.
//   SPLIT: 3-MFMA hi/lo bf16 product (~fp32 accuracy).
//   Two operand sets switched by N-range (n0 >= N1 -> set 2).
//   Split-K via blockIdx.z * kchunk.
//   CMODE 0: C[gr*ldc+col] = acc + bias[col]
//   CMODE 1: atomicAdd(&C[gr*ldc+col], acc)            (bias pre-seeded)
//   CMODE 2: b=gr&63, t=gr>>6; C[(b*T+t)*V + col] = acc + bias[col]
// ---------------------------------------------------------------------------
template<int BM, int BN, int WR, int WC, bool SPLIT, bool B_BF16, int CMODE>
__launch_bounds__(256)
__global__ void gemm_bt(const float* __restrict__ A1, const void* __restrict__ B1,
                        int ldb1, const float* __restrict__ bias1, int K1, int N1,
                        float* __restrict__ C1, int ldc1,
                        const float* __restrict__ A2, const void* __restrict__ B2,
                        int ldb2, const float* __restrict__ bias2, int K2,
                        float* __restrict__ C2, int ldc2, int kchunk)
{
    constexpr int LDK = 40;                       // padded LDS row (bf16 elems), 80B
    constexpr int ASZ = (SPLIT ? 2 : 1) * BM * LDK;
    constexpr int BSZ = (SPLIT ? 2 : 1) * BN * LDK;
    __shared__ ushort_t lds[ASZ + BSZ];
    ushort_t* ldsAh = lds;
    ushort_t* ldsAl = lds + BM * LDK;
    ushort_t* ldsBh = lds + ASZ;
    ushort_t* ldsBl = lds + ASZ + BN * LDK;

    const int tid = threadIdx.x;
    const int m0  = blockIdx.y * BM;
    const int n0  = blockIdx.x * BN;
    const int kz  = blockIdx.z;

    const float* A = A1; const void* Bv = B1; const float* bias = bias1;
    float* C = C1; int ldc = ldc1; int ldb = ldb1;
    int K = K1; int bn0 = n0;
    if (A2 != nullptr && n0 >= N1) {
        A = A2; Bv = B2; bias = bias2; K = K2; bn0 = n0 - N1;
        C = C2; ldc = ldc2; ldb = ldb2;
    }

    constexpr int MF = BM / WR / 16;
    constexpr int NF = BN / WC / 16;
    const int wid  = tid >> 6;
    const int wrow = wid / WC, wcol = wid % WC;
    const int mW = wrow * (BM / WR);
    const int nW = wcol * (BN / WC);
    const int lane = tid & 63;
    const int lr = lane & 15;
    const int lk = lane >> 4;

    f32x4 acc[MF][NF];
    #pragma unroll
    for (int i = 0; i < MF; i++)
        #pragma unroll
        for (int j = 0; j < NF; j++)
            acc[i][j] = (f32x4){0.f, 0.f, 0.f, 0.f};

    const int kbeg = kz * kchunk;
    const int kend = (kbeg + kchunk < K) ? (kbeg + kchunk) : K;

    for (int k0 = kbeg; k0 < kend; k0 += 32) {
        __syncthreads();
        // ---- stage A tile [BM x 32] ----
        for (int c = tid; c < BM * 4; c += 256) {
            int row = c >> 2, slot = c & 3;
            const float* src = A + (size_t)(m0 + row) * K + k0 + slot * 8;
            float4 x0 = *(const float4*)src;
            float4 x1 = *(const float4*)(src + 4);
            uint4 hv;
            hv.x = pk2(x0.x, x0.y); hv.y = pk2(x0.z, x0.w);
            hv.z = pk2(x1.x, x1.y); hv.w = pk2(x1.z, x1.w);
            *(uint4*)&ldsAh[row * LDK + slot * 8] = hv;
            if (SPLIT) {
                uint4 lv;
                lv.x = pk2(x0.x - bf2f((ushort_t)(hv.x & 0xffff)), x0.y - bf2f((ushort_t)(hv.x >> 16)));
                lv.y = pk2(x0.z - bf2f((ushort_t)(hv.y & 0xffff)), x0.w - bf2f((ushort_t)(hv.y >> 16)));
                lv.z = pk2(x1.x - bf2f((ushort_t)(hv.z & 0xffff)), x1.y - bf2f((ushort_t)(hv.z >> 16)));
                lv.w = pk2(x1.z - bf2f((ushort_t)(hv.w & 0xffff)), x1.w - bf2f((ushort_t)(hv.w >> 16)));
                *(uint4*)&ldsAl[row * LDK + slot * 8] = lv;
            }
        }
        // ---- stage B tile [BN x 32] ----
        for (int c = tid; c < BN * 4; c += 256) {
            int row = c >> 2, slot = c & 3;
            if (B_BF16) {
                const ushort_t* src = (const ushort_t*)Bv + (size_t)(bn0 + row) * ldb + k0 + slot * 8;
                *(uint4*)&ldsBh[row * LDK + slot * 8] = *(const uint4*)src;
            } else {
                const float* src = (const float*)Bv + (size_t)(bn0 + row) * ldb + k0 + slot * 8;
                float4 x0 = *(const float4*)src;
                float4 x1 = *(const float4*)(src + 4);
                uint4 hv;
                hv.x = pk2(x0.x, x0.y); hv.y = pk2(x0.z, x0.w);
                hv.z = pk2(x1.x, x1.y); hv.w = pk2(x1.z, x1.w);
                *(uint4*)&ldsBh[row * LDK + slot * 8] = hv;
                if (SPLIT) {
                    uint4 lv;
                    lv.x = pk2(x0.x - bf2f((ushort_t)(hv.x & 0xffff)), x0.y - bf2f((ushort_t)(hv.x >> 16)));
                    lv.y = pk2(x0.z - bf2f((ushort_t)(hv.y & 0xffff)), x0.w - bf2f((ushort_t)(hv.y >> 16)));
                    lv.z = pk2(x1.x - bf2f((ushort_t)(hv.z & 0xffff)), x1.y - bf2f((ushort_t)(hv.z >> 16)));
                    lv.w = pk2(x1.z - bf2f((ushort_t)(hv.w & 0xffff)), x1.w - bf2f((ushort_t)(hv.w >> 16)));
                    *(uint4*)&ldsBl[row * LDK + slot * 8] = lv;
                }
            }
        }
        __syncthreads();
        // ---- fragments + MFMA ----
        bf16x8 aH[MF], bH[NF], aL[MF], bL[NF];
        #pragma unroll
        for (int i = 0; i < MF; i++) {
            aH[i] = *(const bf16x8*)&ldsAh[(mW + i * 16 + lr) * LDK + lk * 8];
            if (SPLIT) aL[i] = *(const bf16x8*)&ldsAl[(mW + i * 16 + lr) * LDK + lk * 8];
        }
        #pragma unroll
        for (int j = 0; j < NF; j++) {
            bH[j] = *(const bf16x8*)&ldsBh[(nW + j * 16 + lr) * LDK + lk * 8];
            if (SPLIT) bL[j] = *(const bf16x8*)&ldsBl[(nW + j * 16 + lr) * LDK + lk * 8];
        }
        #pragma unroll
        for (int i = 0; i < MF; i++)
            #pragma unroll
            for (int j = 0; j < NF; j++) {
                acc[i][j] = __builtin_amdgcn_mfma_f32_16x16x32_bf16(aH[i], bH[j], acc[i][j], 0, 0, 0);
                if (SPLIT) {
                    acc[i][j] = __builtin_amdgcn_mfma_f32_16x16x32_bf16(aH[i], bL[j], acc[i][j], 0, 0, 0);
                    acc[i][j] = __builtin_amdgcn_mfma_f32_16x16x32_bf16(aL[i], bH[j], acc[i][j], 0, 0, 0);
                }
            }
    }
    // ---- epilogue: C/D layout col = lane&15, row = (lane>>4)*4 + reg ----
    #pragma unroll
    for (int i = 0; i < MF; i++)
        #pragma unroll
        for (int j = 0; j < NF; j++)
            #pragma unroll
            for (int r = 0; r < 4; r++) {
                int gr  = m0 + mW + i * 16 + lk * 4 + r;
                int lc  = nW + j * 16 + lr;
                int col = bn0 + lc;
                float v = acc[i][j][r];
                if (CMODE == 0) {
                    C[(size_t)gr * ldc + col] = v + bias[col];
                } else if (CMODE == 1) {
                    atomicAdd(&C[(size_t)gr * ldc + col], v);
                } else {
                    int b = gr & 63, t = gr >> 6;
                    C[((size_t)(b * T_ + t)) * V_ + col] = v + bias[col];
                }
            }
}

// ---------------------------------------------------------------------------
__global__ __launch_bounds__(256) void cast_bf16_k(const float* __restrict__ in,
                                                   ushort_t* __restrict__ out, int n8)
{
    int i = blockIdx.x * 256 + threadIdx.x;
    if (i < n8) {
        float4 a = ((const float4*)in)[2 * i];
        float4 b = ((const float4*)in)[2 * i + 1];
        uint4 v;
        v.x = pk2(a.x, a.y); v.y = pk2(a.z, a.w);
        v.z = pk2(b.x, b.y); v.w = pk2(b.z, b.w);
        ((uint4*)out)[i] = v;
    }
}

// gather teacher-forced embeddings: E[t*64+b, :] = emb_W[tok(t,b)]
__global__ __launch_bounds__(256) void gather_k(const int* __restrict__ target,
                                                const float* __restrict__ emb_W,
                                                float* __restrict__ E)
{
    int idx = blockIdx.x * 256 + threadIdx.x;   // T*B*256 float4 slots
    int r = idx >> 8, c4 = idx & 255;
    int t = r >> 6, b = r & 63;
    int tok = (t == 0) ? 0 : target[b * T_ + t - 1];
    ((float4*)(E + (size_t)r * H_))[c4] = ((const float4*)(emb_W + (size_t)tok * H_))[c4];
}

// seed qbuf with Wa_b, ghbuf with b_hh (broadcast over batch)
__global__ __launch_bounds__(256) void seed_k(const float* __restrict__ Wa_b,
                                              const float* __restrict__ b_hh,
                                              float* __restrict__ qbuf,
                                              float* __restrict__ ghbuf)
{
    int i = blockIdx.x * 256 + threadIdx.x;     // B*H
    int b = i >> 10, g = i & 1023;
    qbuf[i] = Wa_b[g];
    ghbuf[(size_t)b * 3072 + g]        = b_hh[g];
    ghbuf[(size_t)b * 3072 + 1024 + g] = b_hh[1024 + g];
    ghbuf[(size_t)b * 3072 + 2048 + g] = b_hh[2048 + g];
}

// score[b,s] = Va . tanh(q[b]+Uk[b,s]) + Va_b
__global__ __launch_bounds__(256) void score_k(const float* __restrict__ Uk,
                                               const float* __restrict__ q,
                                               const float* __restrict__ Va_w,
                                               const float* __restrict__ Va_b,
                                               float* __restrict__ scores)
{
    int s = blockIdx.x, b = blockIdx.y;
    int tid = threadIdx.x;
    float4 u  = ((const float4*)(Uk + ((size_t)b * S_ + s) * H_))[tid];
    float4 qq = ((const float4*)(q + (size_t)b * H_))[tid];
    float4 v  = ((const float4*)Va_w)[tid];
    float acc = v.x * tanhf(u.x + qq.x) + v.y * tanhf(u.y + qq.y)
              + v.z * tanhf(u.z + qq.z) + v.w * tanhf(u.w + qq.w);
    for (int off = 32; off > 0; off >>= 1) acc += __shfl_down(acc, off, 64);
    __shared__ float part[4];
    if ((tid & 63) == 0) part[tid >> 6] = acc;
    __syncthreads();
    if (tid == 0) scores[b * S_ + s] = part[0] + part[1] + part[2] + part[3] + Va_b[0];
}

// softmax over S + ctx = w @ enc + write attn row
__global__ __launch_bounds__(256) void softctx_k(const float* __restrict__ scores,
                                                 const float* __restrict__ enc,
                                                 float* __restrict__ ctx,
                                                 float* __restrict__ attn_out, int t)
{
    int hc = blockIdx.x, b = blockIdx.y;
    int tid = threadIdx.x;
    __shared__ float sc[S_], el[S_];
    if (tid < S_) sc[tid] = scores[b * S_ + tid];
    __syncthreads();
    float mx = -1e30f;
    for (int s = 0; s < S_; s++) mx = fmaxf(mx, sc[s]);
    if (tid < S_) el[tid] = expf(sc[tid] - mx);
    __syncthreads();
    float sum = 0.f;
    for (int s = 0; s < S_; s++) sum += el[s];
    float inv = 1.f / sum;
    int h = hc * 256 + tid;
    const float* ep = enc + (size_t)b * S_ * H_ + h;
    float acc = 0.f;
    for (int s = 0; s < S_; s++) acc += el[s] * ep[(size_t)s * H_];
    ctx[(size_t)b * H_ + h] = acc * inv;
    if (hc == 0 && tid < S_) attn_out[((size_t)b * T_ + t) * S_ + tid] = el[tid] * inv;
}

// GRU combine: gi = giemb[t] (emb part + ctx part accumulated), gh = ghbuf.
// Writes h_next into Hall[(t+1)*B + b], seeds qbuf/ghbuf for the next step.
__global__ __launch_bounds__(256) void combine_k(const float* __restrict__ giemb_t,
                                                 const float* __restrict__ ghbuf_in,
                                                 const float* __restrict__ hprev,
                                                 float* __restrict__ hnext,
                                                 float* __restrict__ out_hidden,
                                                 const float* __restrict__ Wa_b,
                                                 const float* __restrict__ b_hh,
                                                 float* __restrict__ qbuf,
                                                 float* __restrict__ ghbuf)
{
    int i = blockIdx.x * 256 + threadIdx.x;   // B*H
    int b = i >> 10, g = i & 1023;
    const float* gi = giemb_t + (size_t)b * 3072;
    const float* gh = ghbuf_in + (size_t)b * 3072;
    float ir = gi[g], iz = gi[g + 1024], in = gi[g + 2048];
    float hr = gh[g], hz = gh[g + 1024], hn_ = gh[g + 2048];
    float h = hprev[i];
    float r = 1.f / (1.f + expf(-(ir + hr)));
    float z = 1.f / (1.f + expf(-(iz + hz)));
    float n = tanhf(in + r * hn_);
    float hn = (1.f - z) * n + z * h;
    hnext[i] = hn;
    if (out_hidden) out_hidden[i] = hn;
    // seed next step
    qbuf[i] = Wa_b[g];
    ghbuf[(size_t)b * 3072 + g]        = b_hh[g];
    ghbuf[(size_t)b * 3072 + 1024 + g] = b_hh[1024 + g];
    ghbuf[(size_t)b * 3072 + 2048 + g] = b_hh[2048 + g];
}

// in-place log_softmax over V per row (float4 loads)
__global__ __launch_bounds__(256) void lsm_k(float* __restrict__ out)
{
    float4* p = (float4*)(out + (size_t)blockIdx.x * V_);
    int tid = threadIdx.x;
    float mx = -1e30f, sm = 0.f;
    for (int v = tid; v < V_ / 4; v += 256) {
        float4 x = p[v];
        float xs[4] = {x.x, x.y, x.z, x.w};
        #pragma unroll
        for (int j = 0; j < 4; j++) {
            float m2 = fmaxf(mx, xs[j]);
            sm = sm * expf(mx - m2) + expf(xs[j] - m2);
            mx = m2;
        }
    }
    for (int off = 32; off > 0; off >>= 1) {
        float mo = __shfl_down(mx, off, 64);
        float so = __shfl_down(sm, off, 64);
        float m2 = fmaxf(mx, mo);
        sm = sm * expf(mx - m2) + so * expf(mo - m2);
        mx = m2;
    }
    __shared__ float pm[4], ps[4];
    __shared__ float lse_s;
    if ((tid & 63) == 0) { pm[tid >> 6] = mx; ps[tid >> 6] = sm; }
    __syncthreads();
    if (tid == 0) {
        float m = pm[0], s = ps[0];
        for (int i = 1; i < 4; i++) {
            float m2 = fmaxf(m, pm[i]);
            s = s * expf(m - m2) + ps[i] * expf(pm[i] - m2);
            m = m2;
        }
        lse_s = m + logf(s);
    }
    __syncthreads();
    float lse = lse_s;
    for (int v = tid; v < V_ / 4; v += 256) {
        float4 x = p[v];
        x.x -= lse; x.y -= lse; x.z -= lse; x.w -= lse;
        p[v] = x;
    }
}

// ---------------------------------------------------------------------------
extern "C" void kernel_launch(void* const* d_in, const int* in_sizes, int n_in,
                              void* d_out, int out_size, void* d_ws, size_t ws_size,
                              hipStream_t stream)
{
    (void)in_sizes; (void)n_in; (void)out_size; (void)ws_size;
    const float* enc    = (const float*)d_in[0];
    const float* hidden = (const float*)d_in[1];
    const int*   target = (const int*)d_in[2];
    const float* emb_W  = (const float*)d_in[3];
    const float* Wa_w   = (const float*)d_in[4];
    const float* Wa_b   = (const float*)d_in[5];
    const float* Ua_w   = (const float*)d_in[6];
    const float* Ua_b   = (const float*)d_in[7];
    const float* Va_w   = (const float*)d_in[8];
    const float* Va_b   = (const float*)d_in[9];
    const float* W_ih   = (const float*)d_in[10];
    const float* W_hh   = (const float*)d_in[11];
    const float* b_ih   = (const float*)d_in[12];
    const float* b_hh   = (const float*)d_in[13];
    const float* out_W  = (const float*)d_in[14];
    const float* out_b  = (const float*)d_in[15];

    float* out_logits = (float*)d_out;                       // [B,T,V]
    float* out_hidden = out_logits + (size_t)B_ * T_ * V_;   // [B,H]
    float* out_attn   = out_hidden + (size_t)B_ * H_;        // [B,T,S]

    char* w = (char*)d_ws;
    ushort_t* outW_bf = (ushort_t*)w;  w += (size_t)V_ * H_ * 2;
    float* Uk     = (float*)w;         w += (size_t)B_ * S_ * H_ * 4;
    float* Hall   = (float*)w;         w += (size_t)(T_ + 1) * B_ * H_ * 4;  // h_0..h_10
    float* giemb  = (float*)w;         w += (size_t)T_ * B_ * 3 * H_ * 4;    // gi per step
    float* E      = (float*)w;         w += (size_t)T_ * B_ * H_ * 4;
    float* qbuf   = (float*)w;         w += (size_t)B_ * H_ * 4;
    float* ghbuf  = (float*)w;         w += (size_t)B_ * 3 * H_ * 4;
    float* scores = (float*)w;         w += (size_t)B_ * S_ * 4;
    float* ctx    = (float*)w;         w += (size_t)B_ * H_ * 4;

    // ---- pre-pass ----
    cast_bf16_k<<<V_ * H_ / 8 / 256, 256, 0, stream>>>(out_W, outW_bf, V_ * H_ / 8);
    gather_k<<<T_ * B_, 256, 0, stream>>>(target, emb_W, E);
    // Uk = enc @ Ua^T + Ua_b
    gemm_bt<128, 128, 2, 2, true, false, 0><<<dim3(H_ / 128, B_ * S_ / 128, 1), 256, 0, stream>>>(
        enc, (const void*)Ua_w, H_, Ua_b, H_, 1 << 30, Uk, H_,
        nullptr, nullptr, 0, nullptr, 0, nullptr, 0, H_);
    // giemb = E @ W_ih[:, :H]^T + b_ih   (for all T steps)
    gemm_bt<128, 128, 2, 2, true, false, 0><<<dim3(3 * H_ / 128, T_ * B_ / 128, 1), 256, 0, stream>>>(
        E, (const void*)W_ih, 2 * H_, b_ih, H_, 1 << 30, giemb, 3 * H_,
        nullptr, nullptr, 0, nullptr, 0, nullptr, 0, H_);
    hipMemcpyAsync(Hall, hidden, (size_t)B_ * H_ * 4, hipMemcpyDeviceToDevice, stream);
    seed_k<<<B_ * H_ / 256, 256, 0, stream>>>(Wa_b, b_hh, qbuf, ghbuf);

    // ---- recurrence ----
    for (int t = 0; t < T_; t++) {
        float* hprev = Hall + (size_t)t * B_ * H_;
        float* hnext = Hall + (size_t)(t + 1) * B_ * H_;
        float* gi_t  = giemb + (size_t)t * B_ * 3 * H_;
        // [q | gh] += h @ [Wa ; W_hh]^T   (split-K=4, atomic into seeded bufs)
        gemm_bt<64, 64, 1, 4, true, false, 1><<<dim3(4096 / 64, 1, 4), 256, 0, stream>>>(
            hprev, (const void*)Wa_w, H_, nullptr, H_, H_, qbuf, H_,
            hprev, (const void*)W_hh, H_, nullptr, H_, ghbuf, 3 * H_, 256);
        score_k<<<dim3(S_, B_), 256, 0, stream>>>(Uk, qbuf, Va_w, Va_b, scores);
        softctx_k<<<dim3(H_ / 256, B_), 256, 0, stream>>>(scores, enc, ctx, out_attn, t);
        // gi[t] += ctx @ W_ih[:, H:]^T   (split-K=4, atomic)
        gemm_bt<64, 64, 1, 4, true, false, 1><<<dim3(3 * H_ / 64, 1, 4), 256, 0, stream>>>(
            ctx, (const void*)(W_ih + H_), 2 * H_, nullptr, H_, 1 << 30, gi_t, 3 * H_,
            nullptr, nullptr, 0, nullptr, 0, nullptr, 0, 256);
        combine_k<<<B_ * H_ / 256, 256, 0, stream>>>(
            gi_t, ghbuf, hprev, hnext, (t == T_ - 1) ? out_hidden : nullptr,
            Wa_b, b_hh, qbuf, ghbuf);
    }

    // ---- deferred logits: [T*B,H] @ outW^T, row (t*64+b) -> out[b,t,:] ----
    gemm_bt<128, 128, 2, 2, false, true, 2><<<dim3(V_ / 128, T_ * B_ / 128, 1), 256, 0, stream>>>(
        Hall + (size_t)B_ * H_, (const void*)outW_bf, H_, out_b, H_, 1 << 30, out_logits, 0,
        nullptr, nullptr, 0, nullptr, 0, nullptr, 0, H_);
    lsm_k<<<B_ * T_, 256, 0, stream>>>(out_logits);
}

// Round 7
// 988.946 us; speedup vs baseline: 2.9461x; 1.2018x over previous
//
#include <hip/hip_runtime.h>

#define B_  64
#define S_  128
#define H_  1024
#define V_  32000
#define T_  10

typedef unsigned short ushort_t;
typedef unsigned int uint32;
typedef __attribute__((ext_vector_type(8))) short bf16x8;
typedef __attribute__((ext_vector_type(4))) float f32x4;

__device__ __forceinline__ ushort_t f2bf(float x) {
    uint32 u = __float_as_uint(x);
    u += 0x7fffu + ((u >> 16) & 1u);
    return (ushort_t)(u >> 16);
}
__device__ __forceinline__ float bf2f(ushort_t h) {
    return __uint_as_float(((uint32)h) << 16);
}
__device__ __forceinline__ uint32 pk2(float a, float b) {
    return (uint32)f2bf(a) | ((uint32)f2bf(b) << 16);
}

typedef const __attribute__((address_space(1))) void gas_void;
typedef __attribute__((address_space(3))) void las_void;
__device__ __forceinline__ void gload_lds16(const ushort_t* g, ushort_t* l) {
    __builtin_amdgcn_global_load_lds((gas_void*)g, (las_void*)l, 16, 0, 0);
}

// ---------------------------------------------------------------------------
// bf16 MFMA GEMM, m97-structure: C[M,N] = A @ Bt^T (+bias)
//  A: bf16 hi(/lo) via global_load_lds, or f32 (AF32) split-staged in VALU.
//  B: bf16 hi(/lo) via global_load_lds. SPLIT: 3-MFMA hi/lo (~fp32 accuracy).
//  Split-K: blockIdx.z chunk -> C + z*czstride (partials, no atomics).
//  CMODE 0: C[gr*ldc+col] = acc (+bias)       CMODE 2: logits scatter (+bias)
// ---------------------------------------------------------------------------
template<int BM, int BN, int WC, bool SPLIT, bool AF32, int CMODE>
__launch_bounds__(256)
__global__ void gemm_bf(const float* __restrict__ Af,
                        const ushort_t* __restrict__ Ah, const ushort_t* __restrict__ Al,
                        int lda,
                        const ushort_t* __restrict__ Bh, const ushort_t* __restrict__ Bl,
                        int ldb,
                        int K, int kchunk,
                        const float* __restrict__ bias,
                        float* __restrict__ C, int ldc, size_t czstride)
{
    constexpr int WR = 4 / WC;
    constexpr int MF = BM / WR / 16;
    constexpr int NF = BN / WC / 16;
    __shared__ __align__(16) ushort_t lds[(SPLIT ? 2 : 1) * (BM + BN) * 32];
    ushort_t* ldsAh = lds;
    ushort_t* ldsAl = lds + BM * 32;
    ushort_t* ldsBh = lds + (SPLIT ? 2 : 1) * BM * 32;
    ushort_t* ldsBl = ldsBh + BN * 32;

    const int tid  = threadIdx.x;
    const int wid  = tid >> 6;
    const int lane = tid & 63;
    const int lr   = lane & 15;
    const int lk   = lane >> 4;
    const int m0   = blockIdx.y * BM;
    const int n0   = blockIdx.x * BN;
    const int wrow = wid / WC, wcol = wid % WC;
    const int mW   = wrow * (BM / WR);
    const int nW   = wcol * (BN / WC);

    f32x4 acc[MF][NF];
    #pragma unroll
    for (int i = 0; i < MF; i++)
        #pragma unroll
        for (int j = 0; j < NF; j++)
            acc[i][j] = (f32x4){0.f, 0.f, 0.f, 0.f};

    const int kbeg = blockIdx.z * kchunk;
    const int kend = (kbeg + kchunk < K) ? (kbeg + kchunk) : K;

    for (int k0 = kbeg; k0 < kend; k0 += 32) {
        __syncthreads();
        // ---- stage A [BM x 32] ----
        if constexpr (AF32) {
            #pragma unroll
            for (int p = 0; p < BM * 4 / 256; p++) {
                int c = p * 256 + tid, row = c >> 2, slot = c & 3;
                const float* src = Af + (size_t)(m0 + row) * lda + k0 + slot * 8;
                float4 x0 = *(const float4*)src;
                float4 x1 = *(const float4*)(src + 4);
                uint4 hv;
                hv.x = pk2(x0.x, x0.y); hv.y = pk2(x0.z, x0.w);
                hv.z = pk2(x1.x, x1.y); hv.w = pk2(x1.z, x1.w);
                *(uint4*)&ldsAh[row * 32 + slot * 8] = hv;
                if constexpr (SPLIT) {
                    uint4 lv;
                    lv.x = pk2(x0.x - bf2f((ushort_t)(hv.x & 0xffff)), x0.y - bf2f((ushort_t)(hv.x >> 16)));
                    lv.y = pk2(x0.z - bf2f((ushort_t)(hv.y & 0xffff)), x0.w - bf2f((ushort_t)(hv.y >> 16)));
                    lv.z = pk2(x1.x - bf2f((ushort_t)(hv.z & 0xffff)), x1.y - bf2f((ushort_t)(hv.z >> 16)));
                    lv.w = pk2(x1.z - bf2f((ushort_t)(hv.w & 0xffff)), x1.w - bf2f((ushort_t)(hv.w >> 16)));
                    *(uint4*)&ldsAl[row * 32 + slot * 8] = lv;
                }
            }
        } else {
            for (int is = wid; is < BM / 16; is += 4) {
                int row = is * 16 + (lane >> 2), chk = lane & 3;
                size_t off = (size_t)(m0 + row) * lda + k0 + chk * 8;
                gload_lds16(Ah + off, &ldsAh[is * 512]);
                if constexpr (SPLIT) gload_lds16(Al + off, &ldsAl[is * 512]);
            }
        }
        // ---- stage B [BN x 32] ----
        for (int is = wid; is < BN / 16; is += 4) {
            int row = is * 16 + (lane >> 2), chk = lane & 3;
            size_t off = (size_t)(n0 + row) * ldb + k0 + chk * 8;
            gload_lds16(Bh + off, &ldsBh[is * 512]);
            if constexpr (SPLIT) gload_lds16(Bl + off, &ldsBl[is * 512]);
        }
        __syncthreads();
        // ---- fragments + MFMA ----
        bf16x8 aH[MF], bH[NF], aL[MF], bL[NF];
        #pragma unroll
        for (int i = 0; i < MF; i++) {
            aH[i] = *(const bf16x8*)&ldsAh[(mW + i * 16 + lr) * 32 + lk * 8];
            if constexpr (SPLIT) aL[i] = *(const bf16x8*)&ldsAl[(mW + i * 16 + lr) * 32 + lk * 8];
        }
        #pragma unroll
        for (int j = 0; j < NF; j++) {
            bH[j] = *(const bf16x8*)&ldsBh[(nW + j * 16 + lr) * 32 + lk * 8];
            if constexpr (SPLIT) bL[j] = *(const bf16x8*)&ldsBl[(nW + j * 16 + lr) * 32 + lk * 8];
        }
        #pragma unroll
        for (int i = 0; i < MF; i++)
            #pragma unroll
            for (int j = 0; j < NF; j++) {
                acc[i][j] = __builtin_amdgcn_mfma_f32_16x16x32_bf16(aH[i], bH[j], acc[i][j], 0, 0, 0);
                if constexpr (SPLIT) {
                    acc[i][j] = __builtin_amdgcn_mfma_f32_16x16x32_bf16(aH[i], bL[j], acc[i][j], 0, 0, 0);
                    acc[i][j] = __builtin_amdgcn_mfma_f32_16x16x32_bf16(aL[i], bH[j], acc[i][j], 0, 0, 0);
                }
            }
    }
    // ---- epilogue: C/D layout col = lane&15, row = (lane>>4)*4 + reg ----
    float* Cz = C + (size_t)blockIdx.z * czstride;
    #pragma unroll
    for (int i = 0; i < MF; i++)
        #pragma unroll
        for (int j = 0; j < NF; j++)
            #pragma unroll
            for (int r = 0; r < 4; r++) {
                int gr  = m0 + mW + i * 16 + lk * 4 + r;
                int col = n0 + nW + j * 16 + lr;
                float v = acc[i][j][r];
                if (CMODE == 0) {
                    if (bias) v += bias[col];
                    Cz[(size_t)gr * ldc + col] = v;
                } else {
                    int b = gr & 63, t = gr >> 6;
                    C[((size_t)(b * T_ + t)) * V_ + col] = v + bias[col];
                }
            }
}

// ---------------------------------------------------------------------------
__global__ __launch_bounds__(256) void cast_bf16_k(const float* __restrict__ in,
                                                   ushort_t* __restrict__ out, int n8)
{
    int i = blockIdx.x * 256 + threadIdx.x;
    if (i < n8) {
        float4 a = ((const float4*)in)[2 * i];
        float4 b = ((const float4*)in)[2 * i + 1];
        uint4 v;
        v.x = pk2(a.x, a.y); v.y = pk2(a.z, a.w);
        v.z = pk2(b.x, b.y); v.w = pk2(b.z, b.w);
        ((uint4*)out)[i] = v;
    }
}

__global__ __launch_bounds__(256) void cast_hilo_k(const float* __restrict__ in,
                                                   ushort_t* __restrict__ hi,
                                                   ushort_t* __restrict__ lo, int n8)
{
    int i = blockIdx.x * 256 + threadIdx.x;
    if (i < n8) {
        float4 a = ((const float4*)in)[2 * i];
        float4 b = ((const float4*)in)[2 * i + 1];
        uint4 hv, lv;
        hv.x = pk2(a.x, a.y); hv.y = pk2(a.z, a.w);
        hv.z = pk2(b.x, b.y); hv.w = pk2(b.z, b.w);
        lv.x = pk2(a.x - bf2f((ushort_t)(hv.x & 0xffff)), a.y - bf2f((ushort_t)(hv.x >> 16)));
        lv.y = pk2(a.z - bf2f((ushort_t)(hv.y & 0xffff)), a.w - bf2f((ushort_t)(hv.y >> 16)));
        lv.z = pk2(b.x - bf2f((ushort_t)(hv.z & 0xffff)), b.y - bf2f((ushort_t)(hv.z >> 16)));
        lv.w = pk2(b.z - bf2f((ushort_t)(hv.w & 0xffff)), b.w - bf2f((ushort_t)(hv.w >> 16)));
        ((uint4*)hi)[i] = hv;
        ((uint4*)lo)[i] = lv;
    }
}

// gather teacher-forced embeddings -> hi/lo bf16, rows r = t*64+b
__global__ __launch_bounds__(256) void gatherhl_k(const int* __restrict__ target,
                                                  const float* __restrict__ emb_W,
                                                  ushort_t* __restrict__ Eh,
                                                  ushort_t* __restrict__ El)
{
    int idx = blockIdx.x * 256 + threadIdx.x;   // 640*128
    int r = idx >> 7, c8 = idx & 127;
    int t = r >> 6, b = r & 63;
    int tok = (t == 0) ? 0 : target[b * T_ + t - 1];
    const float* src = emb_W + (size_t)tok * H_ + c8 * 8;
    float4 a = *(const float4*)src;
    float4 c = *(const float4*)(src + 4);
    uint4 hv, lv;
    hv.x = pk2(a.x, a.y); hv.y = pk2(a.z, a.w);
    hv.z = pk2(c.x, c.y); hv.w = pk2(c.z, c.w);
    lv.x = pk2(a.x - bf2f((ushort_t)(hv.x & 0xffff)), a.y - bf2f((ushort_t)(hv.x >> 16)));
    lv.y = pk2(a.z - bf2f((ushort_t)(hv.y & 0xffff)), a.w - bf2f((ushort_t)(hv.y >> 16)));
    lv.z = pk2(c.x - bf2f((ushort_t)(hv.z & 0xffff)), c.y - bf2f((ushort_t)(hv.z >> 16)));
    lv.w = pk2(c.z - bf2f((ushort_t)(hv.w & 0xffff)), c.w - bf2f((ushort_t)(hv.w >> 16)));
    ((uint4*)(Eh + (size_t)r * H_))[c8] = hv;
    ((uint4*)(El + (size_t)r * H_))[c8] = lv;
}

// score[b,s] = Va . tanh(q[b]+Uk[b,s]) + Va_b ; q = sum_kz qgh_part + Wa_b
__global__ __launch_bounds__(256) void score_k(const float* __restrict__ Uk,
                                               const float* __restrict__ qgh_part,
                                               const float* __restrict__ Wa_b,
                                               const float* __restrict__ Va_w,
                                               const float* __restrict__ Va_b,
                                               float* __restrict__ scores)
{
    int s = blockIdx.x, b = blockIdx.y;
    int tid = threadIdx.x;
    float4 qq = ((const float4*)Wa_b)[tid];
    #pragma unroll
    for (int kz = 0; kz < 4; kz++) {
        float4 p = ((const float4*)(qgh_part + (size_t)kz * B_ * 4096 + (size_t)b * 4096))[tid];
        qq.x += p.x; qq.y += p.y; qq.z += p.z; qq.w += p.w;
    }
    float4 u = ((const float4*)(Uk + ((size_t)b * S_ + s) * H_))[tid];
    float4 v = ((const float4*)Va_w)[tid];
    float acc = v.x * tanhf(u.x + qq.x) + v.y * tanhf(u.y + qq.y)
              + v.z * tanhf(u.z + qq.z) + v.w * tanhf(u.w + qq.w);
    for (int off = 32; off > 0; off >>= 1) acc += __shfl_down(acc, off, 64);
    __shared__ float part[4];
    if ((tid & 63) == 0) part[tid >> 6] = acc;
    __syncthreads();
    if (tid == 0) scores[b * S_ + s] = part[0] + part[1] + part[2] + part[3] + Va_b[0];
}

// softmax over S + ctx = w @ enc (hi/lo out) + attn row
__global__ __launch_bounds__(256) void softctx_k(const float* __restrict__ scores,
                                                 const float* __restrict__ enc,
                                                 ushort_t* __restrict__ ctx_hi,
                                                 ushort_t* __restrict__ ctx_lo,
                                                 float* __restrict__ attn_out, int t)
{
    int hc = blockIdx.x, b = blockIdx.y;
    int tid = threadIdx.x;
    __shared__ float sc[S_], el[S_];
    if (tid < S_) sc[tid] = scores[b * S_ + tid];
    __syncthreads();
    float mx = -1e30f;
    for (int s = 0; s < S_; s++) mx = fmaxf(mx, sc[s]);
    if (tid < S_) el[tid] = expf(sc[tid] - mx);
    __syncthreads();
    float sum = 0.f;
    for (int s = 0; s < S_; s++) sum += el[s];
    float inv = 1.f / sum;
    int h = hc * 256 + tid;
    const float* ep = enc + (size_t)b * S_ * H_ + h;
    float acc = 0.f;
    for (int s = 0; s < S_; s++) acc += el[s] * ep[(size_t)s * H_];
    acc *= inv;
    ushort_t chi = f2bf(acc);
    ctx_hi[(size_t)b * H_ + h] = chi;
    ctx_lo[(size_t)b * H_ + h] = f2bf(acc - bf2f(chi));
    if (hc == 0 && tid < S_) attn_out[((size_t)b * T_ + t) * S_ + tid] = el[tid] * inv;
}

// GRU combine: gi = giemb[t]+sum gi_part, gh = b_hh+sum qgh_part[...,1024+g]
__global__ __launch_bounds__(256) void combine_k(const float* __restrict__ giemb_t,
                                                 const float* __restrict__ gi_part,
                                                 const float* __restrict__ qgh_part,
                                                 const ushort_t* __restrict__ Hh,
                                                 const ushort_t* __restrict__ Hl,
                                                 int t,
                                                 float* __restrict__ out_hidden,
                                                 const float* __restrict__ b_hh)
{
    int i = blockIdx.x * 256 + threadIdx.x;   // B*H
    int b = i >> 10, g = i & 1023;
    float ir = giemb_t[(size_t)b * 3072 + g];
    float iz = giemb_t[(size_t)b * 3072 + 1024 + g];
    float in = giemb_t[(size_t)b * 3072 + 2048 + g];
    float hr = b_hh[g], hz = b_hh[1024 + g], hn_ = b_hh[2048 + g];
    #pragma unroll
    for (int kz = 0; kz < 4; kz++) {
        const float* gp = gi_part + (size_t)kz * B_ * 3072 + (size_t)b * 3072;
        ir += gp[g]; iz += gp[1024 + g]; in += gp[2048 + g];
        const float* qp = qgh_part + (size_t)kz * B_ * 4096 + (size_t)b * 4096 + 1024;
        hr += qp[g]; hz += qp[1024 + g]; hn_ += qp[2048 + g];
    }
    float h = bf2f(Hh[(size_t)t * B_ * H_ + i]) + bf2f(Hl[(size_t)t * B_ * H_ + i]);
    float r = 1.f / (1.f + expf(-(ir + hr)));
    float z = 1.f / (1.f + expf(-(iz + hz)));
    float n = tanhf(in + r * hn_);
    float hn = (1.f - z) * n + z * h;
    ushort_t hih = f2bf(hn);
    ushort_t* Hhw = (ushort_t*)Hh; ushort_t* Hlw = (ushort_t*)Hl;
    Hhw[(size_t)(t + 1) * B_ * H_ + i] = hih;
    Hlw[(size_t)(t + 1) * B_ * H_ + i] = f2bf(hn - bf2f(hih));
    if (out_hidden) out_hidden[i] = hn;
}

// in-place log_softmax over V per row
__global__ __launch_bounds__(1024) void lsm_k(float* __restrict__ out)
{
    float4* p = (float4*)(out + (size_t)blockIdx.x * V_);
    int tid = threadIdx.x;
    float mx = -1e30f, sm = 0.f;
    for (int v = tid; v < V_ / 4; v += 1024) {
        float4 x = p[v];
        float xs[4] = {x.x, x.y, x.z, x.w};
        #pragma unroll
        for (int j = 0; j < 4; j++) {
            float m2 = fmaxf(mx, xs[j]);
            sm = sm * expf(mx - m2) + expf(xs[j] - m2);
            mx = m2;
        }
    }
    for (int off = 32; off > 0; off >>= 1) {
        float mo = __shfl_down(mx, off, 64);
        float so = __shfl_down(sm, off, 64);
        float m2 = fmaxf(mx, mo);
        sm = sm * expf(mx - m2) + so * expf(mo - m2);
        mx = m2;
    }
    __shared__ float pm[16], ps[16];
    __shared__ float lse_s;
    if ((tid & 63) == 0) { pm[tid >> 6] = mx; ps[tid >> 6] = sm; }
    __syncthreads();
    if (tid == 0) {
        float m = pm[0], s = ps[0];
        for (int i = 1; i < 16; i++) {
            float m2 = fmaxf(m, pm[i]);
            s = s * expf(m - m2) + ps[i] * expf(pm[i] - m2);
            m = m2;
        }
        lse_s = m + logf(s);
    }
    __syncthreads();
    float lse = lse_s;
    for (int v = tid; v < V_ / 4; v += 1024) {
        float4 x = p[v];
        x.x -= lse; x.y -= lse; x.z -= lse; x.w -= lse;
        p[v] = x;
    }
}

// ---------------------------------------------------------------------------
extern "C" void kernel_launch(void* const* d_in, const int* in_sizes, int n_in,
                              void* d_out, int out_size, void* d_ws, size_t ws_size,
                              hipStream_t stream)
{
    (void)in_sizes; (void)n_in; (void)out_size; (void)ws_size;
    const float* enc    = (const float*)d_in[0];
    const float* hidden = (const float*)d_in[1];
    const int*   target = (const int*)d_in[2];
    const float* emb_W  = (const float*)d_in[3];
    const float* Wa_w   = (const float*)d_in[4];
    const float* Wa_b   = (const float*)d_in[5];
    const float* Ua_w   = (const float*)d_in[6];
    const float* Ua_b   = (const float*)d_in[7];
    const float* Va_w   = (const float*)d_in[8];
    const float* Va_b   = (const float*)d_in[9];
    const float* W_ih   = (const float*)d_in[10];
    const float* W_hh   = (const float*)d_in[11];
    const float* b_ih   = (const float*)d_in[12];
    const float* b_hh   = (const float*)d_in[13];
    const float* out_W  = (const float*)d_in[14];
    const float* out_b  = (const float*)d_in[15];

    float* out_logits = (float*)d_out;                       // [B,T,V]
    float* out_hidden = out_logits + (size_t)B_ * T_ * V_;   // [B,H]
    float* out_attn   = out_hidden + (size_t)B_ * H_;        // [B,T,S]

    char* w = (char*)d_ws;
    auto alloc = [&](size_t bytes) { char* p = w; w += (bytes + 255) & ~(size_t)255; return p; };
    ushort_t* outW_bf = (ushort_t*)alloc((size_t)V_ * H_ * 2);
    float*    Uk      = (float*)alloc((size_t)B_ * S_ * H_ * 4);
    ushort_t* Ua_hi   = (ushort_t*)alloc((size_t)H_ * H_ * 2);
    ushort_t* Ua_lo   = (ushort_t*)alloc((size_t)H_ * H_ * 2);
    ushort_t* Wih_hi  = (ushort_t*)alloc((size_t)3 * H_ * 2 * H_ * 2);
    ushort_t* Wih_lo  = (ushort_t*)alloc((size_t)3 * H_ * 2 * H_ * 2);
    ushort_t* Wc_hi   = (ushort_t*)alloc((size_t)4 * H_ * H_ * 2);   // [Wa;W_hh]
    ushort_t* Wc_lo   = (ushort_t*)alloc((size_t)4 * H_ * H_ * 2);
    ushort_t* E_hi    = (ushort_t*)alloc((size_t)T_ * B_ * H_ * 2);
    ushort_t* E_lo    = (ushort_t*)alloc((size_t)T_ * B_ * H_ * 2);
    ushort_t* H_hi    = (ushort_t*)alloc((size_t)(T_ + 1) * B_ * H_ * 2);
    ushort_t* H_lo    = (ushort_t*)alloc((size_t)(T_ + 1) * B_ * H_ * 2);
    float*    giemb   = (float*)alloc((size_t)T_ * B_ * 3 * H_ * 4);
    float*    gi_part = (float*)alloc((size_t)4 * B_ * 3 * H_ * 4);
    float*    qgh_part= (float*)alloc((size_t)4 * B_ * 4 * H_ * 4);
    ushort_t* ctx_hi  = (ushort_t*)alloc((size_t)B_ * H_ * 2);
    ushort_t* ctx_lo  = (ushort_t*)alloc((size_t)B_ * H_ * 2);
    float*    scores  = (float*)alloc((size_t)B_ * S_ * 4);

    // ---- pre-pass casts (all independent, streaming) ----
    cast_bf16_k<<<V_ * H_ / 8 / 256, 256, 0, stream>>>(out_W, outW_bf, V_ * H_ / 8);
    cast_hilo_k<<<H_ * H_ / 8 / 256, 256, 0, stream>>>(Ua_w, Ua_hi, Ua_lo, H_ * H_ / 8);
    cast_hilo_k<<<3 * H_ * 2 * H_ / 8 / 256, 256, 0, stream>>>(W_ih, Wih_hi, Wih_lo, 3 * H_ * 2 * H_ / 8);
    cast_hilo_k<<<H_ * H_ / 8 / 256, 256, 0, stream>>>(Wa_w, Wc_hi, Wc_lo, H_ * H_ / 8);
    cast_hilo_k<<<3 * H_ * H_ / 8 / 256, 256, 0, stream>>>(W_hh, Wc_hi + (size_t)H_ * H_,
                                                           Wc_lo + (size_t)H_ * H_, 3 * H_ * H_ / 8);
    cast_hilo_k<<<B_ * H_ / 8 / 256, 256, 0, stream>>>(hidden, H_hi, H_lo, B_ * H_ / 8);
    gatherhl_k<<<T_ * B_ * H_ / 8 / 256, 256, 0, stream>>>(target, emb_W, E_hi, E_lo);

    // Uk = enc @ Ua^T + Ua_b  (A from f32, split)
    gemm_bf<128, 128, 2, true, true, 0><<<dim3(H_ / 128, B_ * S_ / 128, 1), 256, 0, stream>>>(
        enc, nullptr, nullptr, H_, Ua_hi, Ua_lo, H_, H_, H_, Ua_b, Uk, H_, 0);
    // giemb = E @ W_ih[:, :H]^T + b_ih  (all steps)
    gemm_bf<128, 128, 2, true, false, 0><<<dim3(3 * H_ / 128, T_ * B_ / 128, 1), 256, 0, stream>>>(
        nullptr, E_hi, E_lo, H_, Wih_hi, Wih_lo, 2 * H_, H_, H_, b_ih, giemb, 3 * H_, 0);

    // ---- recurrence ----
    for (int t = 0; t < T_; t++) {
        float* gi_t = giemb + (size_t)t * B_ * 3 * H_;
        const ushort_t* hh = H_hi + (size_t)t * B_ * H_;
        const ushort_t* hl = H_lo + (size_t)t * B_ * H_;
        // qgh_part[kz] = h @ [Wa ; W_hh]^T   (split-K=4, partial stores)
        gemm_bf<64, 64, 4, true, false, 0><<<dim3(4 * H_ / 64, 1, 4), 256, 0, stream>>>(
            nullptr, hh, hl, H_, Wc_hi, Wc_lo, H_, H_, H_ / 4, nullptr,
            qgh_part, 4 * H_, (size_t)B_ * 4 * H_);
        score_k<<<dim3(S_, B_), 256, 0, stream>>>(Uk, qgh_part, Wa_b, Va_w, Va_b, scores);
        softctx_k<<<dim3(H_ / 256, B_), 256, 0, stream>>>(scores, enc, ctx_hi, ctx_lo, out_attn, t);
        // gi_part[kz] = ctx @ W_ih[:, H:]^T   (split-K=4, partial stores)
        gemm_bf<64, 64, 4, true, false, 0><<<dim3(3 * H_ / 64, 1, 4), 256, 0, stream>>>(
            nullptr, ctx_hi, ctx_lo, H_, Wih_hi + H_, Wih_lo + H_, 2 * H_, H_, H_ / 4, nullptr,
            gi_part, 3 * H_, (size_t)B_ * 3 * H_);
        combine_k<<<B_ * H_ / 256, 256, 0, stream>>>(
            gi_t, gi_part, qgh_part, H_hi, H_lo, t,
            (t == T_ - 1) ? out_hidden : nullptr, b_hh);
    }

    // ---- deferred logits: rows t*64+b of H (steps 1..10) @ outW^T ----
    gemm_bf<128, 128, 2, false, false, 2><<<dim3(V_ / 128, T_ * B_ / 128, 1), 256, 0, stream>>>(
        nullptr, H_hi + (size_t)B_ * H_, nullptr, H_, outW_bf, nullptr, H_, H_, H_,
        out_b, out_logits, 0, 0);
    lsm_k<<<B_ * T_, 1024, 0, stream>>>(out_logits);
}